// Round 1
// baseline (8537.721 us; speedup 1.0000x reference)
//
#include <hip/hip_runtime.h>
#include <math.h>

#define BB 64
#define SS 512
#define EE 512
#define HH 1024

// workspace layout:
// INP  [S][H/4][B] float4 : inp[t][j4*4+c][b] -> INP[((t*256+j4)*64+b)] component c
// hA/hB [H/4][B] float4   : h[j4*4+c][b]  (transposed hidden state; "j" this step == "k" next step)
// hsel  [H/4][B] float4
// lin   [H/4][B] float4

#define DOT4(acc, u, v) acc += (u).x*(v).x + (u).y*(v).y + (u).z*(v).z + (u).w*(v).w

__global__ __launch_bounds__(512) void gemm1_kernel(
    const int* __restrict__ x, const float* __restrict__ emb,
    const float* __restrict__ Wi, const float* __restrict__ bi,
    float4* __restrict__ INP)
{
    int t    = blockIdx.y;
    int lane = threadIdx.x & 63;                                   // batch b
    int wave = __builtin_amdgcn_readfirstlane(threadIdx.x >> 6);   // 0..7
    int j4   = blockIdx.x * 8 + wave;                              // 0..255

    int row = x[lane * SS + t];
    const float4* e  = reinterpret_cast<const float4*>(emb + (size_t)row * EE);
    const float4* w0 = reinterpret_cast<const float4*>(Wi + (size_t)(j4*4+0) * EE);
    const float4* w1 = reinterpret_cast<const float4*>(Wi + (size_t)(j4*4+1) * EE);
    const float4* w2 = reinterpret_cast<const float4*>(Wi + (size_t)(j4*4+2) * EE);
    const float4* w3 = reinterpret_cast<const float4*>(Wi + (size_t)(j4*4+3) * EE);

    float a0 = 0.f, a1 = 0.f, a2 = 0.f, a3 = 0.f;
    for (int k4 = 0; k4 < EE/4; ++k4) {
        float4 ev = e[k4];
        float4 w;
        w = w0[k4]; DOT4(a0, ev, w);
        w = w1[k4]; DOT4(a1, ev, w);
        w = w2[k4]; DOT4(a2, ev, w);
        w = w3[k4]; DOT4(a3, ev, w);
    }
    float4 bv = *reinterpret_cast<const float4*>(bi + j4*4);
    float4 r;
    r.x = fmaxf(a0 + bv.x, 0.f);
    r.y = fmaxf(a1 + bv.y, 0.f);
    r.z = fmaxf(a2 + bv.z, 0.f);
    r.w = fmaxf(a3 + bv.w, 0.f);
    INP[((size_t)t * 256 + j4) * 64 + lane] = r;
}

__global__ __launch_bounds__(512) void step_kernel(
    const float4* __restrict__ hin, float4* __restrict__ hout,
    const float4* __restrict__ inp_t,
    const float* __restrict__ Wf, const float* __restrict__ bf,
    const float* __restrict__ Wh, const float* __restrict__ bh,
    const int* __restrict__ lengths, float4* __restrict__ hsel, int t)
{
    __shared__ float pf[8][4][64];
    __shared__ float ph[8][4][64];

    int lane = threadIdx.x & 63;                                   // batch b
    int kq   = __builtin_amdgcn_readfirstlane(threadIdx.x >> 6);   // 0..7, K-split
    int jg   = blockIdx.x;                                         // 0..255, cols jg*4..+3

    const float4* wf0 = reinterpret_cast<const float4*>(Wf + (size_t)(jg*4+0)*HH) + kq*32;
    const float4* wf1 = reinterpret_cast<const float4*>(Wf + (size_t)(jg*4+1)*HH) + kq*32;
    const float4* wf2 = reinterpret_cast<const float4*>(Wf + (size_t)(jg*4+2)*HH) + kq*32;
    const float4* wf3 = reinterpret_cast<const float4*>(Wf + (size_t)(jg*4+3)*HH) + kq*32;
    const float4* wh0 = reinterpret_cast<const float4*>(Wh + (size_t)(jg*4+0)*HH) + kq*32;
    const float4* wh1 = reinterpret_cast<const float4*>(Wh + (size_t)(jg*4+1)*HH) + kq*32;
    const float4* wh2 = reinterpret_cast<const float4*>(Wh + (size_t)(jg*4+2)*HH) + kq*32;
    const float4* wh3 = reinterpret_cast<const float4*>(Wh + (size_t)(jg*4+3)*HH) + kq*32;
    const float4* hp  = hin + (size_t)kq * 32 * 64;

    float f0=0.f,f1=0.f,f2=0.f,f3=0.f, g0=0.f,g1=0.f,g2=0.f,g3=0.f;
    #pragma unroll 4
    for (int k4 = 0; k4 < 32; ++k4) {
        float4 hv = hp[k4*64 + lane];
        float4 w;
        w = wf0[k4]; DOT4(f0, hv, w);
        w = wf1[k4]; DOT4(f1, hv, w);
        w = wf2[k4]; DOT4(f2, hv, w);
        w = wf3[k4]; DOT4(f3, hv, w);
        w = wh0[k4]; DOT4(g0, hv, w);
        w = wh1[k4]; DOT4(g1, hv, w);
        w = wh2[k4]; DOT4(g2, hv, w);
        w = wh3[k4]; DOT4(g3, hv, w);
    }
    pf[kq][0][lane]=f0; pf[kq][1][lane]=f1; pf[kq][2][lane]=f2; pf[kq][3][lane]=f3;
    ph[kq][0][lane]=g0; ph[kq][1][lane]=g1; ph[kq][2][lane]=g2; ph[kq][3][lane]=g3;
    __syncthreads();

    if (threadIdx.x < 64) {
        int b = threadIdx.x;
        float sf[4], sh[4];
        #pragma unroll
        for (int c = 0; c < 4; ++c) { sf[c] = bf[jg*4+c]; sh[c] = bh[jg*4+c]; }
        #pragma unroll
        for (int q = 0; q < 8; ++q) {
            #pragma unroll
            for (int c = 0; c < 4; ++c) { sf[c] += pf[q][c][b]; sh[c] += ph[q][c][b]; }
        }
        float4 iv = inp_t[jg*64 + b];
        float4 hn;
        hn.x = 1.f/(1.f+expf(-sf[0])) + tanhf(sh[0]) * iv.x;
        hn.y = 1.f/(1.f+expf(-sf[1])) + tanhf(sh[1]) * iv.y;
        hn.z = 1.f/(1.f+expf(-sf[2])) + tanhf(sh[2]) * iv.z;
        hn.w = 1.f/(1.f+expf(-sf[3])) + tanhf(sh[3]) * iv.w;
        hout[jg*64 + b] = hn;
        if (t == lengths[b] - 1) hsel[jg*64 + b] = hn;
    }
}

__global__ __launch_bounds__(512) void outproj_kernel(
    const float4* __restrict__ hsel, float4* __restrict__ lin,
    const float* __restrict__ Wo, const float* __restrict__ bo)
{
    __shared__ float pf[8][4][64];

    int lane = threadIdx.x & 63;
    int kq   = __builtin_amdgcn_readfirstlane(threadIdx.x >> 6);
    int jg   = blockIdx.x;

    const float4* w0 = reinterpret_cast<const float4*>(Wo + (size_t)(jg*4+0)*HH) + kq*32;
    const float4* w1 = reinterpret_cast<const float4*>(Wo + (size_t)(jg*4+1)*HH) + kq*32;
    const float4* w2 = reinterpret_cast<const float4*>(Wo + (size_t)(jg*4+2)*HH) + kq*32;
    const float4* w3 = reinterpret_cast<const float4*>(Wo + (size_t)(jg*4+3)*HH) + kq*32;
    const float4* hp = hsel + (size_t)kq * 32 * 64;

    float a0=0.f,a1=0.f,a2=0.f,a3=0.f;
    #pragma unroll 4
    for (int k4 = 0; k4 < 32; ++k4) {
        float4 hv = hp[k4*64 + lane];
        float4 w;
        w = w0[k4]; DOT4(a0, hv, w);
        w = w1[k4]; DOT4(a1, hv, w);
        w = w2[k4]; DOT4(a2, hv, w);
        w = w3[k4]; DOT4(a3, hv, w);
    }
    pf[kq][0][lane]=a0; pf[kq][1][lane]=a1; pf[kq][2][lane]=a2; pf[kq][3][lane]=a3;
    __syncthreads();

    if (threadIdx.x < 64) {
        int b = threadIdx.x;
        float s[4];
        #pragma unroll
        for (int c = 0; c < 4; ++c) s[c] = bo[jg*4+c];
        #pragma unroll
        for (int q = 0; q < 8; ++q) {
            #pragma unroll
            for (int c = 0; c < 4; ++c) s[c] += pf[q][c][b];
        }
        float4 r; r.x=s[0]; r.y=s[1]; r.z=s[2]; r.w=s[3];
        lin[jg*64 + b] = r;
    }
}

__global__ __launch_bounds__(64) void final_kernel(
    const float4* __restrict__ lin, const float* __restrict__ Wlin,
    const float* __restrict__ blin, float* __restrict__ out)
{
    int b = threadIdx.x;
    float l0 = blin[0], l1 = blin[1];
    const float4* w0 = reinterpret_cast<const float4*>(Wlin);
    const float4* w1 = reinterpret_cast<const float4*>(Wlin + HH);
    for (int j4 = 0; j4 < 256; ++j4) {
        float4 v = lin[j4*64 + b];
        float4 w;
        w = w0[j4]; DOT4(l0, v, w);
        w = w1[j4]; DOT4(l1, v, w);
    }
    float m   = fmaxf(l0, l1);
    float lse = m + logf(expf(l0 - m) + expf(l1 - m));
    out[b*2 + 0] = l0 - lse;
    out[b*2 + 1] = l1 - lse;
}

extern "C" void kernel_launch(void* const* d_in, const int* in_sizes, int n_in,
                              void* d_out, int out_size, void* d_ws, size_t ws_size,
                              hipStream_t stream) {
    (void)in_sizes; (void)n_in; (void)out_size; (void)ws_size;
    const int*   x       = (const int*)  d_in[0];
    const int*   lengths = (const int*)  d_in[1];
    const float* emb     = (const float*)d_in[2];
    const float* Wi      = (const float*)d_in[3];
    const float* bi      = (const float*)d_in[4];
    const float* Wf      = (const float*)d_in[5];
    const float* bf      = (const float*)d_in[6];
    const float* Wh      = (const float*)d_in[7];
    const float* bh      = (const float*)d_in[8];
    const float* Wo      = (const float*)d_in[9];
    const float* bo      = (const float*)d_in[10];
    const float* Wlin    = (const float*)d_in[11];
    const float* blin    = (const float*)d_in[12];
    float* out = (float*)d_out;

    char* ws = (char*)d_ws;
    const size_t INP_BYTES = (size_t)SS * 256 * 64 * sizeof(float4); // 128 MiB
    float4* INP  = (float4*)ws;
    float4* hA   = (float4*)(ws + INP_BYTES);
    float4* hB   = hA + 256*64;
    float4* hsel = hB + 256*64;
    float4* lin  = hsel + 256*64;

    hipMemsetAsync(hA, 0, 256*64*sizeof(float4), stream);

    gemm1_kernel<<<dim3(32, 512), 512, 0, stream>>>(x, emb, Wi, bi, INP);

    float4* hin = hA;
    float4* hout = hB;
    for (int t = 0; t < SS; ++t) {
        step_kernel<<<256, 512, 0, stream>>>(hin, hout, INP + (size_t)t*256*64,
                                             Wf, bf, Wh, bh, lengths, hsel, t);
        float4* tmp = hin; hin = hout; hout = tmp;
    }

    outproj_kernel<<<256, 512, 0, stream>>>(hsel, lin, Wo, bo);
    final_kernel<<<1, 64, 0, stream>>>(lin, Wlin, blin, out);
}